// Round 13
// baseline (1943.466 us; speedup 1.0000x reference)
//
#include <hip/hip_runtime.h>
#include <hip/hip_bf16.h>
#include <cstdio>
#include <cstdint>

// Problem constants
#define BB 64
#define TT 512
#define II 512
#define HH 1024
#define G4H 4096   // 4*H
#define TC 256     // timesteps per chunk (2 chunks)

typedef __attribute__((ext_vector_type(8))) short short8b;  // 8 bf16 (4 VGPRs)
typedef __attribute__((ext_vector_type(4))) float f32x4;    // MFMA accumulator
typedef unsigned long long ull;

union U16 { uint4 u; short8b s; };

#define AT_LD32(p)   __hip_atomic_load((p), __ATOMIC_RELAXED, __HIP_MEMORY_SCOPE_AGENT)
#define AT_LD64(p)   __hip_atomic_load((p), __ATOMIC_RELAXED, __HIP_MEMORY_SCOPE_AGENT)
#define AT_ST32(p,v) __hip_atomic_store((p), (v), __ATOMIC_RELAXED, __HIP_MEMORY_SCOPE_AGENT)
#define AT_ST64(p,v) __hip_atomic_store((p), (v), __ATOMIC_RELAXED, __HIP_MEMORY_SCOPE_AGENT)

__device__ __forceinline__ ushort f2bf(float f) {
    union { float f; unsigned u; } x; x.f = f;
    unsigned r = x.u + 0x7FFFu + ((x.u >> 16) & 1u);
    return (ushort)(r >> 16);
}
__device__ __forceinline__ float bf2f(ushort b) {
    union { unsigned u; float f; } x; x.u = ((unsigned)b) << 16;
    return x.f;
}
__device__ __forceinline__ float sigm(float x) { return 1.f / (1.f + __expf(-x)); }
__device__ __forceinline__ float tanh_(float x) { return 2.f / (1.f + __expf(-2.f * x)) - 1.f; }

// ---------------- fused prep: conv x (f32->bf16) + 8 transposes in ONE launch ----
__global__ __launch_bounds__(256) void prep_fused(
    const float* __restrict__ x, ushort* __restrict__ x_bf,
    const float* __restrict__ U0, const float* __restrict__ U1,
    const float* __restrict__ U2, const float* __restrict__ U3,
    ushort* __restrict__ U_t,
    const float* __restrict__ V0, const float* __restrict__ V1,
    const float* __restrict__ V2, const float* __restrict__ V3,
    ushort* __restrict__ V_t)
{
    __shared__ float tile[32][33];
    const int b = blockIdx.x;
    const int tid = threadIdx.x;
    if (b < 2048) {
        int i = (b * 256 + tid) * 4;
        const int n = BB * TT * II;
        const int stride = 2048 * 256 * 4;
        for (; i < n; i += stride) {
            float4 v = *(const float4*)(x + i);
            ushort4 o;
            o.x = f2bf(v.x); o.y = f2bf(v.y); o.z = f2bf(v.z); o.w = f2bf(v.w);
            *(ushort4*)(x_bf + i) = o;
        }
        return;
    }
    const int tx = tid & 31, ty = tid >> 5;
    const float* in; ushort* out; int K, j0, k0;
    if (b < 4096) {
        int u = b - 2048;
        int g = u >> 9, r = u & 511;
        const float* Us[4] = {U0, U1, U2, U3};
        in = Us[g]; out = U_t + (size_t)g * 1024 * 512; K = 512;
        j0 = (r & 31) * 32; k0 = (r >> 5) * 32;
    } else {
        int v = b - 4096;
        int g = v >> 10, r = v & 1023;
        const float* Vs[4] = {V0, V1, V2, V3};
        in = Vs[g]; out = V_t + (size_t)g * 1024 * 1024; K = 1024;
        j0 = (r & 31) * 32; k0 = (r >> 5) * 32;
    }
    #pragma unroll
    for (int i = 0; i < 32; i += 8)
        tile[ty + i][tx] = in[(size_t)(k0 + ty + i) * 1024 + j0 + tx];
    __syncthreads();
    #pragma unroll
    for (int i = 0; i < 32; i += 8)
        out[(size_t)(j0 + ty + i) * K + k0 + tx] = f2bf(tile[tx][ty + i]);
}

// ---------------- phase A: xU(chunk) = x(:, t0:t0+TC, :) @ [U_ig|U_f|U_c|U_o] + b ----
__global__ __launch_bounds__(256) void gemm_xu(
    const ushort* __restrict__ A, const ushort* __restrict__ Bt,
    const float* __restrict__ b0, const float* __restrict__ b1,
    const float* __restrict__ b2, const float* __restrict__ b3,
    ushort* __restrict__ C, int t0)
{
    __shared__ ushort As[128 * 64];
    __shared__ ushort Bs[128 * 64];
    const int m0 = blockIdx.x * 128;
    const int n0 = blockIdx.y * 128;
    const int tid = threadIdx.x;
    const int lane = tid & 63;
    const int wave = tid >> 6;
    const int wm = (wave >> 1) * 64;
    const int wn = (wave & 1) * 64;
    const int kgrp = lane >> 4;

    const ushort* Abase = A + ((size_t)(m0 >> 8) * TT + t0 + (m0 & 255)) * 512;

    f32x4 acc[4][4];
    #pragma unroll
    for (int i = 0; i < 4; ++i)
        #pragma unroll
        for (int j = 0; j < 4; ++j) acc[i][j] = (f32x4){0.f, 0.f, 0.f, 0.f};

    for (int k0 = 0; k0 < 512; k0 += 64) {
        __syncthreads();
        #pragma unroll
        for (int p = 0; p < 4; ++p) {
            int idx = p * 256 + tid;
            int row = idx >> 3;
            int kc  = idx & 7;
            uint4 va = *(const uint4*)(Abase + (size_t)row * 512 + k0 + kc * 8);
            uint4 vb = *(const uint4*)(Bt + (size_t)(n0 + row) * 512 + k0 + kc * 8);
            int bo = (row * 128 + kc * 16) ^ ((row & 7) << 4);
            *(uint4*)((char*)As + bo) = va;
            *(uint4*)((char*)Bs + bo) = vb;
        }
        __syncthreads();
        #pragma unroll
        for (int ks = 0; ks < 2; ++ks) {
            U16 af[4], bfr[4];
            #pragma unroll
            for (int i = 0; i < 4; ++i) {
                int row = wm + i * 16 + (lane & 15);
                int ao = (row * 128 + ks * 64 + kgrp * 16) ^ ((row & 7) << 4);
                af[i].u = *(const uint4*)((const char*)As + ao);
                int col = wn + i * 16 + (lane & 15);
                int bo = (col * 128 + ks * 64 + kgrp * 16) ^ ((col & 7) << 4);
                bfr[i].u = *(const uint4*)((const char*)Bs + bo);
            }
            #pragma unroll
            for (int i = 0; i < 4; ++i)
                #pragma unroll
                for (int j = 0; j < 4; ++j)
                    acc[i][j] = __builtin_amdgcn_mfma_f32_16x16x32_bf16(af[i].s, bfr[j].s, acc[i][j], 0, 0, 0);
        }
    }
    #pragma unroll
    for (int i = 0; i < 4; ++i) {
        #pragma unroll
        for (int j = 0; j < 4; ++j) {
            int row = m0 + wm + i * 16 + (lane >> 4) * 4;
            int col = n0 + wn + j * 16 + (lane & 15);
            int gate = col >> 10;
            const float* bp = (gate == 0) ? b0 : (gate == 1) ? b1 : (gate == 2) ? b2 : b3;
            float bias = bp[col & 1023];
            #pragma unroll
            for (int r = 0; r < 4; ++r)
                C[(size_t)(row + r) * G4H + col] = f2bf(acc[i][j][r] + bias);
        }
    }
}

// ---------------- phase B: persistent recurrent kernel ----------------
// r11 structure + SPLIT-STAGE overlap: all 16 MALL loads issued up front;
// half-A (k<512 of every row) written to LDS -> Bb1 -> MFMA ks 0..15 runs
// while half-B loads are still in flight -> write half-B -> Bb2 -> ks 16..31.
// The second half's MALL latency hides under the first half's MFMA.
// 3 barriers/step (Bb1, Bb2, B5). Halves are disjoint 1024B row-segments.
// hbuf: [parity][grp][row16][1024] bf16; flags: [4 grp][64 slice] x 16 u32 stride.
__global__ __launch_bounds__(256, 1) void lstm_rec(
    const ushort* __restrict__ xU,   // [B*TC][4096] bf16 chunk
    const ushort* __restrict__ V_t,  // [4096][1024] bf16 (V transposed)
    char* __restrict__ hb,           // h double buffer, 256 KB
    float* __restrict__ cbuf,        // [64][1024] f32
    float* __restrict__ out,         // h then c, f32
    unsigned* __restrict__ flags,    // [4][64*16] (64B-strided flags)
    int t0)
{
    __shared__ __align__(16) ushort Vl[64 * 1024];  // 128 KB, permuted cols + swizzled
    __shared__ __align__(16) ushort hl[16 * 1024];  // 32 KB h tile [row][k] swizzled

    const int wgid = blockIdx.x;
    const int grp = wgid >> 6;        // batch group: rows grp*16..+16
    const int slice = wgid & 63;      // h-col slice: cols slice*16..+16
    const int tid = threadIdx.x;
    const int lane = tid & 63;
    const int w = tid >> 6;           // wave 0..3

    // ---- stage V slice into LDS (cols permuted: c <-> (wave=c>>4, jq=(c>>2)&3, gate=c&3))
    #pragma unroll
    for (int p = 0; p < 32; ++p) {
        int idx = p * 256 + tid;  // 0..8191
        int c  = idx >> 7;        // 0..63
        int kc = idx & 127;       // 8-elem k chunk
        int colg = (c & 3) * 1024 + slice * 16 + ((c >> 4) << 2) + ((c >> 2) & 3);
        uint4 v = *(const uint4*)(V_t + (size_t)colg * 1024 + kc * 8);
        int bo = (c * 2048 + kc * 16) ^ ((c & 7) << 4);
        *(uint4*)((char*)Vl + bo) = v;
    }

    // per-lane recurrent-state mapping (C/D layout + 4x4 transpose, verified r9-r11)
    const int myrow = (lane >> 4) * 4 + (lane & 3);    // 0..15
    const int mycol = 4 * w + ((lane >> 2) & 3);       // 0..15 within slice
    const int growf = grp * 16 + myrow;
    const int hcol = slice * 16 + mycol;
    float c_reg = (t0 == 0) ? 0.f : cbuf[(size_t)growf * 1024 + hcol];

    // MFMA fragment constants
    const int kgrp = lane >> 4;               // 0..3 (A k-group)
    const int lrow = lane & 15;               // A row
    const int arow_sw = (lrow & 7) << 4;
    const int bc = w * 16 + (lane & 15);      // Vl col for B frag
    const int bxor = (bc & 7) << 4;
    const int bo_base = bc * 2048 + kgrp * 16;

    __syncthreads();  // Vl staged

    for (int t = t0; t < t0 + TC; ++t) {
        // prefetch xU operands (issued before poll; HBM latency hides under it)
        size_t xbase = ((size_t)growf * TC + (t - t0)) * G4H + hcol;
        ushort xi = xU[xbase], xf = xU[xbase + 1024], xc = xU[xbase + 2048], xo = xU[xbase + 3072];

        // ---- all-wave poll: all 64 producers of this group stored h(t)
        {
            const unsigned tgt = (unsigned)t;
            const unsigned* f = flags + grp * 1024;
            while (!__all((int)(AT_LD32(&f[lane * 16]) >= tgt)))
                __builtin_amdgcn_s_sleep(1);
            asm volatile("" ::: "memory");
        }

        // ---- issue ALL 16 stage loads now (column-half mapping):
        // u = it*256+tid (it<8 -> half A): row = u>>7, colbyte = (u&127)*8 + half*1024
        ull vv[16];
        {
            const char* hsrc = hb + (size_t)(t & 1) * 131072 + grp * 32768;
            #pragma unroll
            for (int it = 0; it < 8; ++it) {
                int u = it * 256 + tid;
                vv[it] = AT_LD64((const ull*)(hsrc + (size_t)(u >> 7) * 2048 + (u & 127) * 8));
            }
            #pragma unroll
            for (int it = 0; it < 8; ++it) {
                int u = it * 256 + tid;
                vv[8 + it] = AT_LD64((const ull*)(hsrc + (size_t)(u >> 7) * 2048 + 1024 + (u & 127) * 8));
            }
        }
        // ---- write half-A (k < 512 of every row)
        #pragma unroll
        for (int it = 0; it < 8; ++it) {
            int u = it * 256 + tid;
            int row = u >> 7;
            int cb  = (u & 127) * 8;
            *(ull*)((char*)hl + ((row * 2048 + cb) ^ ((row & 7) << 4))) = vv[it];
        }
        __syncthreads();  // Bb1: half-A staged

        // ---- MFMA first half (ks 0..15, k-bytes 0..1023) — half-B loads in flight
        f32x4 acc0 = (f32x4){0.f,0.f,0.f,0.f}, acc1 = (f32x4){0.f,0.f,0.f,0.f};
        const char* hlb = (const char*)hl;
        #pragma unroll
        for (int ks = 0; ks < 16; ks += 2) {
            U16 a0, b0, a1, b1;
            a0.u = *(const uint4*)(hlb + ((lrow * 2048 + (ks * 4 + kgrp) * 16) ^ arow_sw));
            b0.u = *(const uint4*)((const char*)Vl + ((bo_base + ks * 64) ^ bxor));
            acc0 = __builtin_amdgcn_mfma_f32_16x16x32_bf16(a0.s, b0.s, acc0, 0, 0, 0);
            a1.u = *(const uint4*)(hlb + ((lrow * 2048 + (ks * 4 + 4 + kgrp) * 16) ^ arow_sw));
            b1.u = *(const uint4*)((const char*)Vl + ((bo_base + ks * 64 + 64) ^ bxor));
            acc1 = __builtin_amdgcn_mfma_f32_16x16x32_bf16(a1.s, b1.s, acc1, 0, 0, 0);
        }

        // ---- write half-B (k >= 512); disjoint from half-A reads
        #pragma unroll
        for (int it = 0; it < 8; ++it) {
            int u = it * 256 + tid;
            int row = u >> 7;
            int cb  = 1024 + (u & 127) * 8;
            *(ull*)((char*)hl + ((row * 2048 + cb) ^ ((row & 7) << 4))) = vv[8 + it];
        }
        __syncthreads();  // Bb2: half-B staged

        // ---- MFMA second half (ks 16..31)
        #pragma unroll
        for (int ks = 16; ks < 32; ks += 2) {
            U16 a0, b0, a1, b1;
            a0.u = *(const uint4*)(hlb + ((lrow * 2048 + (ks * 4 + kgrp) * 16) ^ arow_sw));
            b0.u = *(const uint4*)((const char*)Vl + ((bo_base + ks * 64) ^ bxor));
            acc0 = __builtin_amdgcn_mfma_f32_16x16x32_bf16(a0.s, b0.s, acc0, 0, 0, 0);
            a1.u = *(const uint4*)(hlb + ((lrow * 2048 + (ks * 4 + 4 + kgrp) * 16) ^ arow_sw));
            b1.u = *(const uint4*)((const char*)Vl + ((bo_base + ks * 64 + 64) ^ bxor));
            acc1 = __builtin_amdgcn_mfma_f32_16x16x32_bf16(a1.s, b1.s, acc1, 0, 0, 0);
        }
        float a0 = acc0[0] + acc1[0], a1 = acc0[1] + acc1[1];
        float a2 = acc0[2] + acc1[2], a3 = acc0[3] + acc1[3];

        // ---- 4x4 transpose within each 4-lane cluster (verified r9-r11)
        {
            float b0 = __shfl_xor(a1, 1), b1 = __shfl_xor(a0, 1);
            float b2 = __shfl_xor(a3, 1), b3 = __shfl_xor(a2, 1);
            bool o1 = (lane & 1) != 0;
            a0 = o1 ? b0 : a0;  a1 = o1 ? a1 : b1;
            a2 = o1 ? b2 : a2;  a3 = o1 ? a3 : b3;
            b0 = __shfl_xor(a2, 2); b1 = __shfl_xor(a3, 2);
            b2 = __shfl_xor(a0, 2); b3 = __shfl_xor(a1, 2);
            bool o2 = (lane & 2) != 0;
            a0 = o2 ? b0 : a0;  a1 = o2 ? b1 : a1;
            a2 = o2 ? a2 : b2;  a3 = o2 ? a3 : b3;
        }
        // a0..a3 = gates (input, forget, tilded, output) of (myrow, mycol)

        // ---- gates + state update (wave-local)
        float gi = a0 + bf2f(xi), gf = a1 + bf2f(xf);
        float gc = a2 + bf2f(xc), go = a3 + bf2f(xo);
        float ig = sigm(gi), fg = sigm(gf), ct = tanh_(gc), og = sigm(go);
        c_reg = ig * ct + fg * c_reg;
        float h = og * tanh_(c_reg);
        ushort hbf = f2bf(h);
        // pack 4 consecutive cols (jq=0..3, same row) into the jq==0 lane
        unsigned h1 = __shfl_down((unsigned)hbf, 4);
        unsigned h2 = __shfl_down((unsigned)hbf, 8);
        unsigned h3 = __shfl_down((unsigned)hbf, 12);
        if (((lane >> 2) & 3) == 0) {
            ull pk = (ull)hbf | ((ull)(h1 & 0xffff) << 16)
                   | ((ull)(h2 & 0xffff) << 32) | ((ull)(h3 & 0xffff) << 48);
            AT_ST64((ull*)(hb + (size_t)((t & 1) ^ 1) * 131072 + grp * 32768
                           + myrow * 2048 + (size_t)(slice * 16 + 4 * w) * 2), pk);
        }
        if (t == TT - 1) {
            out[(size_t)growf * 1024 + hcol] = h;
            out[(size_t)BB * HH + (size_t)growf * 1024 + hcol] = c_reg;
        }
        __syncthreads();  // B5: all waves' h stores drained (vmcnt) -> at MALL
        if (tid == 0) AT_ST32(flags + grp * 1024 + slice * 16, (unsigned)(t + 1));
    }

    if (t0 + TC < TT)
        cbuf[(size_t)growf * 1024 + hcol] = c_reg;
}

// ---------------- host ----------------
extern "C" void kernel_launch(void* const* d_in, const int* in_sizes, int n_in,
                              void* d_out, int out_size, void* d_ws, size_t ws_size,
                              hipStream_t stream) {
    const float* x = (const float*)d_in[0];
    const float* U[4] = {(const float*)d_in[1], (const float*)d_in[4], (const float*)d_in[7], (const float*)d_in[10]};
    const float* V[4] = {(const float*)d_in[2], (const float*)d_in[5], (const float*)d_in[8], (const float*)d_in[11]};
    const float* bias[4] = {(const float*)d_in[3], (const float*)d_in[6], (const float*)d_in[9], (const float*)d_in[12]};
    float* out = (float*)d_out;

    const size_t x_elems = (size_t)BB * TT * II;
    size_t off = 0;
    auto alloc = [&](size_t bytes) { size_t o = off; off = (off + bytes + 255) & ~(size_t)255; return o; };
    size_t o_xbf   = alloc(x_elems * 2);
    size_t o_Ut    = alloc((size_t)G4H * II * 2);
    size_t o_Vt    = alloc((size_t)G4H * HH * 2);
    size_t o_xU    = alloc((size_t)BB * TC * G4H * 2);
    size_t o_hbuf  = alloc(262144);                   // [2][4][16][1024] bf16
    size_t o_cbuf  = alloc((size_t)BB * HH * 4);
    size_t o_flags = alloc(4 * 64 * 64);              // 64B-strided flags, 16 KB
    if (ws_size < off) {
        fprintf(stderr, "kernel_launch: ws too small: need %zu have %zu\n", off, ws_size);
        return;
    }
    char* ws = (char*)d_ws;
    ushort* x_bf = (ushort*)(ws + o_xbf);
    ushort* U_t  = (ushort*)(ws + o_Ut);
    ushort* V_t  = (ushort*)(ws + o_Vt);
    ushort* xU   = (ushort*)(ws + o_xU);
    char*   hbuf = ws + o_hbuf;
    float*  cbuf = (float*)(ws + o_cbuf);
    unsigned* flags = (unsigned*)(ws + o_flags);

    // reset replay state: flags -> 0 (poll tgt t=0 passes trivially), h_0 -> 0
    hipMemsetAsync(flags, 0, 4 * 64 * 64, stream);
    hipMemsetAsync(hbuf, 0, 262144, stream);

    prep_fused<<<8192, 256, 0, stream>>>(x, x_bf,
        U[0], U[1], U[2], U[3], U_t,
        V[0], V[1], V[2], V[3], V_t);

    for (int c = 0; c < TT / TC; ++c) {
        int t0 = c * TC;
        gemm_xu<<<dim3(128, 32), 256, 0, stream>>>(x_bf, U_t, bias[0], bias[1], bias[2], bias[3], xU, t0);
        lstm_rec<<<256, 256, 0, stream>>>(xU, V_t, hbuf, cbuf, out, flags, t0);
    }
}

// Round 14
// 1890.712 us; speedup vs baseline: 1.0279x; 1.0279x over previous
//
#include <hip/hip_runtime.h>
#include <hip/hip_bf16.h>
#include <cstdio>
#include <cstdint>

// Problem constants
#define BB 64
#define TT 512
#define II 512
#define HH 1024
#define G4H 4096   // 4*H
#define TC 256     // timesteps per chunk (2 chunks)

typedef __attribute__((ext_vector_type(8))) short short8b;  // 8 bf16 (4 VGPRs)
typedef __attribute__((ext_vector_type(4))) float f32x4;    // MFMA accumulator
typedef unsigned long long ull;

union U16 { uint4 u; short8b s; };

#define AT_LD32(p)   __hip_atomic_load((p), __ATOMIC_RELAXED, __HIP_MEMORY_SCOPE_AGENT)
#define AT_LD64(p)   __hip_atomic_load((p), __ATOMIC_RELAXED, __HIP_MEMORY_SCOPE_AGENT)
#define AT_ST32(p,v) __hip_atomic_store((p), (v), __ATOMIC_RELAXED, __HIP_MEMORY_SCOPE_AGENT)
#define AT_ST64(p,v) __hip_atomic_store((p), (v), __ATOMIC_RELAXED, __HIP_MEMORY_SCOPE_AGENT)

__device__ __forceinline__ ushort f2bf(float f) {
    union { float f; unsigned u; } x; x.f = f;
    unsigned r = x.u + 0x7FFFu + ((x.u >> 16) & 1u);
    return (ushort)(r >> 16);
}
__device__ __forceinline__ float bf2f(ushort b) {
    union { unsigned u; float f; } x; x.u = ((unsigned)b) << 16;
    return x.f;
}
__device__ __forceinline__ float sigm(float x) { return 1.f / (1.f + __expf(-x)); }
__device__ __forceinline__ float tanh_(float x) { return 2.f / (1.f + __expf(-2.f * x)) - 1.f; }

// ---------------- fused prep: conv x (f32->bf16) + 8 transposes in ONE launch ----
__global__ __launch_bounds__(256) void prep_fused(
    const float* __restrict__ x, ushort* __restrict__ x_bf,
    const float* __restrict__ U0, const float* __restrict__ U1,
    const float* __restrict__ U2, const float* __restrict__ U3,
    ushort* __restrict__ U_t,
    const float* __restrict__ V0, const float* __restrict__ V1,
    const float* __restrict__ V2, const float* __restrict__ V3,
    ushort* __restrict__ V_t)
{
    __shared__ float tile[32][33];
    const int b = blockIdx.x;
    const int tid = threadIdx.x;
    if (b < 2048) {
        int i = (b * 256 + tid) * 4;
        const int n = BB * TT * II;
        const int stride = 2048 * 256 * 4;
        for (; i < n; i += stride) {
            float4 v = *(const float4*)(x + i);
            ushort4 o;
            o.x = f2bf(v.x); o.y = f2bf(v.y); o.z = f2bf(v.z); o.w = f2bf(v.w);
            *(ushort4*)(x_bf + i) = o;
        }
        return;
    }
    const int tx = tid & 31, ty = tid >> 5;
    const float* in; ushort* out; int K, j0, k0;
    if (b < 4096) {
        int u = b - 2048;
        int g = u >> 9, r = u & 511;
        const float* Us[4] = {U0, U1, U2, U3};
        in = Us[g]; out = U_t + (size_t)g * 1024 * 512; K = 512;
        j0 = (r & 31) * 32; k0 = (r >> 5) * 32;
    } else {
        int v = b - 4096;
        int g = v >> 10, r = v & 1023;
        const float* Vs[4] = {V0, V1, V2, V3};
        in = Vs[g]; out = V_t + (size_t)g * 1024 * 1024; K = 1024;
        j0 = (r & 31) * 32; k0 = (r >> 5) * 32;
    }
    #pragma unroll
    for (int i = 0; i < 32; i += 8)
        tile[ty + i][tx] = in[(size_t)(k0 + ty + i) * 1024 + j0 + tx];
    __syncthreads();
    #pragma unroll
    for (int i = 0; i < 32; i += 8)
        out[(size_t)(j0 + ty + i) * K + k0 + tx] = f2bf(tile[tx][ty + i]);
}

// ---------------- phase A: xU(chunk) = x(:, t0:t0+TC, :) @ [U_ig|U_f|U_c|U_o] + b ----
__global__ __launch_bounds__(256) void gemm_xu(
    const ushort* __restrict__ A, const ushort* __restrict__ Bt,
    const float* __restrict__ b0, const float* __restrict__ b1,
    const float* __restrict__ b2, const float* __restrict__ b3,
    ushort* __restrict__ C, int t0)
{
    __shared__ ushort As[128 * 64];
    __shared__ ushort Bs[128 * 64];
    const int m0 = blockIdx.x * 128;
    const int n0 = blockIdx.y * 128;
    const int tid = threadIdx.x;
    const int lane = tid & 63;
    const int wave = tid >> 6;
    const int wm = (wave >> 1) * 64;
    const int wn = (wave & 1) * 64;
    const int kgrp = lane >> 4;

    const ushort* Abase = A + ((size_t)(m0 >> 8) * TT + t0 + (m0 & 255)) * 512;

    f32x4 acc[4][4];
    #pragma unroll
    for (int i = 0; i < 4; ++i)
        #pragma unroll
        for (int j = 0; j < 4; ++j) acc[i][j] = (f32x4){0.f, 0.f, 0.f, 0.f};

    for (int k0 = 0; k0 < 512; k0 += 64) {
        __syncthreads();
        #pragma unroll
        for (int p = 0; p < 4; ++p) {
            int idx = p * 256 + tid;
            int row = idx >> 3;
            int kc  = idx & 7;
            uint4 va = *(const uint4*)(Abase + (size_t)row * 512 + k0 + kc * 8);
            uint4 vb = *(const uint4*)(Bt + (size_t)(n0 + row) * 512 + k0 + kc * 8);
            int bo = (row * 128 + kc * 16) ^ ((row & 7) << 4);
            *(uint4*)((char*)As + bo) = va;
            *(uint4*)((char*)Bs + bo) = vb;
        }
        __syncthreads();
        #pragma unroll
        for (int ks = 0; ks < 2; ++ks) {
            U16 af[4], bfr[4];
            #pragma unroll
            for (int i = 0; i < 4; ++i) {
                int row = wm + i * 16 + (lane & 15);
                int ao = (row * 128 + ks * 64 + kgrp * 16) ^ ((row & 7) << 4);
                af[i].u = *(const uint4*)((const char*)As + ao);
                int col = wn + i * 16 + (lane & 15);
                int bo = (col * 128 + ks * 64 + kgrp * 16) ^ ((col & 7) << 4);
                bfr[i].u = *(const uint4*)((const char*)Bs + bo);
            }
            #pragma unroll
            for (int i = 0; i < 4; ++i)
                #pragma unroll
                for (int j = 0; j < 4; ++j)
                    acc[i][j] = __builtin_amdgcn_mfma_f32_16x16x32_bf16(af[i].s, bfr[j].s, acc[i][j], 0, 0, 0);
        }
    }
    #pragma unroll
    for (int i = 0; i < 4; ++i) {
        #pragma unroll
        for (int j = 0; j < 4; ++j) {
            int row = m0 + wm + i * 16 + (lane >> 4) * 4;
            int col = n0 + wn + j * 16 + (lane & 15);
            int gate = col >> 10;
            const float* bp = (gate == 0) ? b0 : (gate == 1) ? b1 : (gate == 2) ? b2 : b3;
            float bias = bp[col & 1023];
            #pragma unroll
            for (int r = 0; r < 4; ++r)
                C[(size_t)(row + r) * G4H + col] = f2bf(acc[i][j][r] + bias);
        }
    }
}

// ---------------- phase B: persistent recurrent kernel (r11 = best known) ----
// 256 WGs x 256 threads = 4 batch groups (16 rows) x 64 hidden slices.
//  (1) ALL-WAVE poll (each wave polls the 64 flags itself) -> no broadcast
//      barrier; (2) stage loads issued IMMEDIATELY after own-wave detect
//      (T14 issue-early/write-late: MALL latency overlaps detect skew);
//  (3) flags padded to one per 64B line (no hot-line store/poll contention).
// 2 barriers/step: Bb (hl staged) and B5 (h-store drain before flag).
// hbuf: [parity][grp][row16][1024] bf16; flags: [4 grp][64 slice] x 16 u32 stride.
__global__ __launch_bounds__(256, 1) void lstm_rec(
    const ushort* __restrict__ xU,   // [B*TC][4096] bf16 chunk
    const ushort* __restrict__ V_t,  // [4096][1024] bf16 (V transposed)
    char* __restrict__ hb,           // h double buffer, 256 KB
    float* __restrict__ cbuf,        // [64][1024] f32
    float* __restrict__ out,         // h then c, f32
    unsigned* __restrict__ flags,    // [4][64*16] (64B-strided flags)
    int t0)
{
    __shared__ __align__(16) ushort Vl[64 * 1024];  // 128 KB, permuted cols + swizzled
    __shared__ __align__(16) ushort hl[16 * 1024];  // 32 KB h tile [row][k] swizzled

    const int wgid = blockIdx.x;
    const int grp = wgid >> 6;        // batch group: rows grp*16..+16
    const int slice = wgid & 63;      // h-col slice: cols slice*16..+16
    const int tid = threadIdx.x;
    const int lane = tid & 63;
    const int w = tid >> 6;           // wave 0..3

    // ---- stage V slice into LDS (cols permuted: c <-> (wave=c>>4, jq=(c>>2)&3, gate=c&3))
    #pragma unroll
    for (int p = 0; p < 32; ++p) {
        int idx = p * 256 + tid;  // 0..8191
        int c  = idx >> 7;        // 0..63
        int kc = idx & 127;       // 8-elem k chunk
        int colg = (c & 3) * 1024 + slice * 16 + ((c >> 4) << 2) + ((c >> 2) & 3);
        uint4 v = *(const uint4*)(V_t + (size_t)colg * 1024 + kc * 8);
        int bo = (c * 2048 + kc * 16) ^ ((c & 7) << 4);
        *(uint4*)((char*)Vl + bo) = v;
    }

    // per-lane recurrent-state mapping (C/D layout + 4x4 transpose, verified r9-r11)
    const int myrow = (lane >> 4) * 4 + (lane & 3);    // 0..15
    const int mycol = 4 * w + ((lane >> 2) & 3);       // 0..15 within slice
    const int growf = grp * 16 + myrow;
    const int hcol = slice * 16 + mycol;
    float c_reg = (t0 == 0) ? 0.f : cbuf[(size_t)growf * 1024 + hcol];

    // MFMA fragment constants
    const int kgrp = lane >> 4;               // 0..3 (A k-group)
    const int lrow = lane & 15;               // A row
    const int arow_sw = (lrow & 7) << 4;
    const int bc = w * 16 + (lane & 15);      // Vl col for B frag
    const int bxor = (bc & 7) << 4;
    const int bo_base = bc * 2048 + kgrp * 16;

    __syncthreads();  // Vl staged

    for (int t = t0; t < t0 + TC; ++t) {
        // prefetch xU operands (issued before poll; HBM latency hides under it)
        size_t xbase = ((size_t)growf * TC + (t - t0)) * G4H + hcol;
        ushort xi = xU[xbase], xf = xU[xbase + 1024], xc = xU[xbase + 2048], xo = xU[xbase + 3072];

        // ---- all-wave poll: all 64 producers of this group stored h(t)
        {
            const unsigned tgt = (unsigned)t;
            const unsigned* f = flags + grp * 1024;
            while (!__all((int)(AT_LD32(&f[lane * 16]) >= tgt)))
                __builtin_amdgcn_s_sleep(1);
            asm volatile("" ::: "memory");
        }

        // ---- issue stage loads NOW (before any barrier): latency overlaps skew
        ull vv[16];
        {
            const char* hsrc = hb + (size_t)(t & 1) * 131072 + grp * 32768;
            #pragma unroll
            for (int it = 0; it < 16; ++it)
                vv[it] = AT_LD64((const ull*)(hsrc + (size_t)(it * 256 + tid) * 8));
        }
        // write into hl (B5 of prev iter already ordered all prev hl reads)
        {
            #pragma unroll
            for (int it = 0; it < 16; ++it) {
                int q = it * 256 + tid;
                int row = q >> 8;
                int cb  = (q & 255) * 8;
                *(ull*)((char*)hl + ((row * 2048 + cb) ^ ((row & 7) << 4))) = vv[it];
            }
        }
        __syncthreads();  // Bb: hl staged

        // ---- h(t) @ V slice: wave w -> 16 rows x (4 h-cols x 4 gates), K=1024
        f32x4 acc0 = (f32x4){0.f,0.f,0.f,0.f}, acc1 = (f32x4){0.f,0.f,0.f,0.f};
        const char* hlb = (const char*)hl;
        #pragma unroll
        for (int ks = 0; ks < 32; ks += 2) {
            U16 a0, b0, a1, b1;
            a0.u = *(const uint4*)(hlb + ((lrow * 2048 + (ks * 4 + kgrp) * 16) ^ arow_sw));
            b0.u = *(const uint4*)((const char*)Vl + ((bo_base + ks * 64) ^ bxor));
            acc0 = __builtin_amdgcn_mfma_f32_16x16x32_bf16(a0.s, b0.s, acc0, 0, 0, 0);
            a1.u = *(const uint4*)(hlb + ((lrow * 2048 + (ks * 4 + 4 + kgrp) * 16) ^ arow_sw));
            b1.u = *(const uint4*)((const char*)Vl + ((bo_base + ks * 64 + 64) ^ bxor));
            acc1 = __builtin_amdgcn_mfma_f32_16x16x32_bf16(a1.s, b1.s, acc1, 0, 0, 0);
        }
        float a0 = acc0[0] + acc1[0], a1 = acc0[1] + acc1[1];
        float a2 = acc0[2] + acc1[2], a3 = acc0[3] + acc1[3];

        // ---- 4x4 transpose within each 4-lane cluster (verified r9-r11)
        {
            float b0 = __shfl_xor(a1, 1), b1 = __shfl_xor(a0, 1);
            float b2 = __shfl_xor(a3, 1), b3 = __shfl_xor(a2, 1);
            bool o1 = (lane & 1) != 0;
            a0 = o1 ? b0 : a0;  a1 = o1 ? a1 : b1;
            a2 = o1 ? b2 : a2;  a3 = o1 ? a3 : b3;
            b0 = __shfl_xor(a2, 2); b1 = __shfl_xor(a3, 2);
            b2 = __shfl_xor(a0, 2); b3 = __shfl_xor(a1, 2);
            bool o2 = (lane & 2) != 0;
            a0 = o2 ? b0 : a0;  a1 = o2 ? b1 : a1;
            a2 = o2 ? a2 : b2;  a3 = o2 ? a3 : b3;
        }
        // a0..a3 = gates (input, forget, tilded, output) of (myrow, mycol)

        // ---- gates + state update (wave-local)
        float gi = a0 + bf2f(xi), gf = a1 + bf2f(xf);
        float gc = a2 + bf2f(xc), go = a3 + bf2f(xo);
        float ig = sigm(gi), fg = sigm(gf), ct = tanh_(gc), og = sigm(go);
        c_reg = ig * ct + fg * c_reg;
        float h = og * tanh_(c_reg);
        ushort hbf = f2bf(h);
        // pack 4 consecutive cols (jq=0..3, same row) into the jq==0 lane
        unsigned h1 = __shfl_down((unsigned)hbf, 4);
        unsigned h2 = __shfl_down((unsigned)hbf, 8);
        unsigned h3 = __shfl_down((unsigned)hbf, 12);
        if (((lane >> 2) & 3) == 0) {
            ull pk = (ull)hbf | ((ull)(h1 & 0xffff) << 16)
                   | ((ull)(h2 & 0xffff) << 32) | ((ull)(h3 & 0xffff) << 48);
            AT_ST64((ull*)(hb + (size_t)((t & 1) ^ 1) * 131072 + grp * 32768
                           + myrow * 2048 + (size_t)(slice * 16 + 4 * w) * 2), pk);
        }
        if (t == TT - 1) {
            out[(size_t)growf * 1024 + hcol] = h;
            out[(size_t)BB * HH + (size_t)growf * 1024 + hcol] = c_reg;
        }
        __syncthreads();  // B5: all waves' h stores drained (vmcnt) -> at MALL
        if (tid == 0) AT_ST32(flags + grp * 1024 + slice * 16, (unsigned)(t + 1));
    }

    if (t0 + TC < TT)
        cbuf[(size_t)growf * 1024 + hcol] = c_reg;
}

// ---------------- host ----------------
extern "C" void kernel_launch(void* const* d_in, const int* in_sizes, int n_in,
                              void* d_out, int out_size, void* d_ws, size_t ws_size,
                              hipStream_t stream) {
    const float* x = (const float*)d_in[0];
    const float* U[4] = {(const float*)d_in[1], (const float*)d_in[4], (const float*)d_in[7], (const float*)d_in[10]};
    const float* V[4] = {(const float*)d_in[2], (const float*)d_in[5], (const float*)d_in[8], (const float*)d_in[11]};
    const float* bias[4] = {(const float*)d_in[3], (const float*)d_in[6], (const float*)d_in[9], (const float*)d_in[12]};
    float* out = (float*)d_out;

    const size_t x_elems = (size_t)BB * TT * II;
    size_t off = 0;
    auto alloc = [&](size_t bytes) { size_t o = off; off = (off + bytes + 255) & ~(size_t)255; return o; };
    size_t o_xbf   = alloc(x_elems * 2);
    size_t o_Ut    = alloc((size_t)G4H * II * 2);
    size_t o_Vt    = alloc((size_t)G4H * HH * 2);
    size_t o_xU    = alloc((size_t)BB * TC * G4H * 2);
    size_t o_hbuf  = alloc(262144);                   // [2][4][16][1024] bf16
    size_t o_cbuf  = alloc((size_t)BB * HH * 4);
    size_t o_flags = alloc(4 * 64 * 64);              // 64B-strided flags, 16 KB
    if (ws_size < off) {
        fprintf(stderr, "kernel_launch: ws too small: need %zu have %zu\n", off, ws_size);
        return;
    }
    char* ws = (char*)d_ws;
    ushort* x_bf = (ushort*)(ws + o_xbf);
    ushort* U_t  = (ushort*)(ws + o_Ut);
    ushort* V_t  = (ushort*)(ws + o_Vt);
    ushort* xU   = (ushort*)(ws + o_xU);
    char*   hbuf = ws + o_hbuf;
    float*  cbuf = (float*)(ws + o_cbuf);
    unsigned* flags = (unsigned*)(ws + o_flags);

    // reset replay state: flags -> 0 (poll tgt t=0 passes trivially), h_0 -> 0
    hipMemsetAsync(flags, 0, 4 * 64 * 64, stream);
    hipMemsetAsync(hbuf, 0, 262144, stream);

    prep_fused<<<8192, 256, 0, stream>>>(x, x_bf,
        U[0], U[1], U[2], U[3], U_t,
        V[0], V[1], V[2], V[3], V_t);

    for (int c = 0; c < TT / TC; ++c) {
        int t0 = c * TC;
        gemm_xu<<<dim3(128, 32), 256, 0, stream>>>(x_bf, U_t, bias[0], bias[1], bias[2], bias[3], xU, t0);
        lstm_rec<<<256, 256, 0, stream>>>(xU, V_t, hbuf, cbuf, out, flags, t0);
    }
}